// Round 7
// baseline (445.257 us; speedup 1.0000x reference)
//
#include <hip/hip_runtime.h>

// ---------------------------------------------------------------------------
// DoubleLayeredEncoder: 2-layer GCN + PReLU + half-sum. N=100k, E=1.6M.
// R7: XCD-privatized segmented ELL (4 segments by blockIdx&3, cap 28/seg;
// counters+rows segment-major so each slab is touched by ~2 XCDs under
// round-robin dispatch -> atomic lines & store lines stop ping-ponging across
// all 8 XCDs). 1 edge/thread build. g1g2 rebalanced to 16 lanes x 8ch (uint4).
//
// Pipeline: memset(cnt) -> k_gemm1 -> k_ell -> k_dinv -> k_g1g2 -> k_g2h
// ---------------------------------------------------------------------------

#define SEG 4
#define CAP 28

__device__ __forceinline__ unsigned bf16rne(float x) {
    unsigned u = __float_as_uint(x);
    return (u + 0x7FFFu + ((u >> 16) & 1u)) >> 16;
}
__device__ __forceinline__ unsigned pack2bf(float a, float b) {
    return bf16rne(a) | (bf16rne(b) << 16);
}
__device__ __forceinline__ float bflo(unsigned u) { return __uint_as_float(u << 16); }
__device__ __forceinline__ float bfhi(unsigned u) { return __uint_as_float(u & 0xFFFF0000u); }

// ---- segmented ELL build: 1 edge/thread, segment = blockIdx & 3 ------------
__global__ __launch_bounds__(256) void k_ell(const int* __restrict__ src,
                                             const int* __restrict__ dst,
                                             const int* __restrict__ et,
                                             const float* __restrict__ w,
                                             int* __restrict__ cnt,
                                             int2* __restrict__ ell, int E, int n) {
    int e = blockIdx.x * 256 + threadIdx.x;
    if (e >= E) return;
    int seg = blockIdx.x & (SEG - 1);
    int d = dst[e];
    int pos = atomicAdd(&cnt[seg * n + d], 1);
    if (pos < CAP)
        ell[((size_t)seg * n + d) * CAP + pos] =
            make_int2(src[e] | (et[e] << 24), __float_as_int(w[e]));
}

// ---- weighted degrees + rsqrt + packed segment lengths, 16 lanes/node ------
__global__ __launch_bounds__(256) void k_dinv(const int* __restrict__ cnt,
                                              const int2* __restrict__ ell,
                                              float* __restrict__ dinv1,
                                              float* __restrict__ dinv2,
                                              unsigned* __restrict__ lensw, int n) {
    int t = threadIdx.x;
    int d = blockIdx.x * 16 + (t >> 4);
    int g = t & 15;
    float s1 = 0.f, s2 = 0.f;
    int l0 = 0, l1 = 0, l2 = 0, l3 = 0;
    if (d < n) {
        int c = (g < SEG) ? min(cnt[g * n + d], CAP) : 0;
        l0 = __shfl(c, 0, 16); l1 = __shfl(c, 1, 16);
        l2 = __shfl(c, 2, 16); l3 = __shfl(c, 3, 16);
        int ls[SEG] = {l0, l1, l2, l3};
        for (int seg = 0; seg < SEG; seg++) {
            int len = ls[seg];
            const int2* row = ell + ((size_t)seg * n + d) * CAP;
            for (int kk = g; kk < len; kk += 16) {
                int2 e = row[kk];
                s1 += __int_as_float(e.y);
                s2 += (float)(((unsigned)e.x) >> 24);
            }
        }
    }
#pragma unroll
    for (int o = 8; o >= 1; o >>= 1) {
        s1 += __shfl_xor(s1, o, 16);
        s2 += __shfl_xor(s2, o, 16);
    }
    if (d < n && g == 0) {
        dinv1[d] = rsqrtf(1.0f + s1);
        dinv2[d] = rsqrtf(1.0f + s2);
        lensw[d] = (unsigned)l0 | ((unsigned)l1 << 8) |
                   ((unsigned)l2 << 16) | ((unsigned)l3 << 24);
    }
}

// ---- gemm1: xb1 = bf16(x @ W1) UNSCALED. 32 rows/block, W from L2. --------
__global__ __launch_bounds__(256) void k_gemm1(const float* __restrict__ x,
                                               const float* __restrict__ W,
                                               unsigned* __restrict__ xb1, int n) {
    __shared__ float xs[128 * 32];   // [k][r], 16 KB, lane-fast row map
    int t = threadIdx.x;
    int row0 = blockIdx.x * 32;
    const float4* x4 = (const float4*)x;
#pragma unroll
    for (int i = 0; i < 4; i++) {
        int q = t + 256 * i;
        int r = q & 31;
        int c4 = (q >> 5) << 2;
        int row = row0 + r;
        float4 v = make_float4(0.f, 0.f, 0.f, 0.f);
        if (row < n) v = x4[row * 32 + (c4 >> 2)];
        xs[(c4 + 0) * 32 + r] = v.x;
        xs[(c4 + 1) * 32 + r] = v.y;
        xs[(c4 + 2) * 32 + r] = v.z;
        xs[(c4 + 3) * 32 + r] = v.w;
    }
    __syncthreads();

    int c4 = (t & 31) << 2;
    int r4 = (t >> 5) << 2;
    const float4* W4 = (const float4*)W;
    float acc[4][4] = {};
#pragma unroll 8
    for (int k = 0; k < 128; k++) {
        float4 xv = *(const float4*)&xs[k * 32 + r4];
        float4 wv = W4[k * 32 + (c4 >> 2)];
        acc[0][0] += xv.x * wv.x; acc[0][1] += xv.x * wv.y; acc[0][2] += xv.x * wv.z; acc[0][3] += xv.x * wv.w;
        acc[1][0] += xv.y * wv.x; acc[1][1] += xv.y * wv.y; acc[1][2] += xv.y * wv.z; acc[1][3] += xv.y * wv.w;
        acc[2][0] += xv.z * wv.x; acc[2][1] += xv.z * wv.y; acc[2][2] += xv.z * wv.z; acc[2][3] += xv.z * wv.w;
        acc[3][0] += xv.w * wv.x; acc[3][1] += xv.w * wv.y; acc[3][2] += xv.w * wv.z; acc[3][3] += xv.w * wv.w;
    }
#pragma unroll
    for (int i = 0; i < 4; i++) {
        int row = row0 + r4 + i;
        if (row < n) {
            uint2 o = make_uint2(pack2bf(acc[i][0], acc[i][1]),
                                 pack2bf(acc[i][2], acc[i][3]));
            ((uint2*)xb1)[row * 32 + (c4 >> 2)] = o;
        }
    }
}

// ---- gather1 (+dinv, bias, PReLU) fused with gemm2 -> xb2 -----------------
// 16 lanes/node x 8 ch (uint4), 16 nodes/block. W2 bf16 in LDS.
__global__ __launch_bounds__(256) void k_g1g2(const unsigned* __restrict__ lensw,
                                              const int2* __restrict__ ell,
                                              const unsigned* __restrict__ xb1,
                                              const float* __restrict__ dinv1,
                                              const float* __restrict__ b,
                                              const float* __restrict__ alpha,
                                              const float* __restrict__ W2,
                                              unsigned* __restrict__ xb2, int n) {
    __shared__ unsigned W2s[128 * 32];   // bf16-packed col pairs, 16 KB
    __shared__ float hs[16 * 128];       // h1 tile, 8 KB
    int t = threadIdx.x;

    const float2* W22 = (const float2*)W2;
#pragma unroll
    for (int i = 0; i < 16; i++) {
        int idx = t + 256 * i;           // 0..4095
        float2 v = W22[idx];
        W2s[idx] = pack2bf(v.x, v.y);
    }

    int nl = t >> 4;                     // node slot 0..15
    int g = t & 15;
    int d = blockIdx.x * 16 + nl;
    bool active = d < n;
    unsigned lw = active ? lensw[d] : 0u;
    const uint4* x4 = (const uint4*)xb1; // row = 16 uint4 = 256 B

    float a0 = 0.f, a1 = 0.f, a2 = 0.f, a3 = 0.f;
    float a4 = 0.f, a5 = 0.f, a6 = 0.f, a7 = 0.f;
    for (int seg = 0; seg < SEG; seg++) {
        int len = (lw >> (seg * 8)) & 0xFF;
        const int2* rowp = ell + ((size_t)seg * n + d) * CAP;
        for (int k0 = 0; k0 < len; k0 += 16) {
            int kk = k0 + g;
            int2 ent = make_int2(0, 0);
            float cf = 0.f;
            if (kk < len) {
                ent = rowp[kk];
                cf = __int_as_float(ent.y) * dinv1[ent.x & 0xFFFFFF];  // w*dinv1[src]
            }
            int m = min(16, len - k0);
            for (int j = 0; j < m; j++) {
                int pej = __shfl(ent.x, j, 16);
                float cj = __shfl(cf, j, 16);
                int s = pej & 0xFFFFFF;
                uint4 q = x4[(size_t)s * 16 + g];
                a0 += bflo(q.x) * cj; a1 += bfhi(q.x) * cj;
                a2 += bflo(q.y) * cj; a3 += bfhi(q.y) * cj;
                a4 += bflo(q.z) * cj; a5 += bfhi(q.z) * cj;
                a6 += bflo(q.w) * cj; a7 += bfhi(q.w) * cj;
            }
        }
    }

    if (active) {
        float di = dinv1[d];
        uint4 sq = x4[(size_t)d * 16 + g];
        int c8 = g << 3;
        float4 blo = *(const float4*)&b[c8], bhi = *(const float4*)&b[c8 + 4];
        float4 alo = *(const float4*)&alpha[c8], ahi = *(const float4*)&alpha[c8 + 4];
        float v0 = di * (a0 + bflo(sq.x) * di) + blo.x; v0 = v0 >= 0.f ? v0 : alo.x * v0;
        float v1 = di * (a1 + bfhi(sq.x) * di) + blo.y; v1 = v1 >= 0.f ? v1 : alo.y * v1;
        float v2 = di * (a2 + bflo(sq.y) * di) + blo.z; v2 = v2 >= 0.f ? v2 : alo.z * v2;
        float v3 = di * (a3 + bfhi(sq.y) * di) + blo.w; v3 = v3 >= 0.f ? v3 : alo.w * v3;
        float v4 = di * (a4 + bflo(sq.z) * di) + bhi.x; v4 = v4 >= 0.f ? v4 : ahi.x * v4;
        float v5 = di * (a5 + bfhi(sq.z) * di) + bhi.y; v5 = v5 >= 0.f ? v5 : ahi.y * v5;
        float v6 = di * (a6 + bflo(sq.w) * di) + bhi.z; v6 = v6 >= 0.f ? v6 : ahi.z * v6;
        float v7 = di * (a7 + bfhi(sq.w) * di) + bhi.w; v7 = v7 >= 0.f ? v7 : ahi.w * v7;
        *(float4*)&hs[nl * 128 + c8] = make_float4(v0, v1, v2, v3);
        *(float4*)&hs[nl * 128 + c8 + 4] = make_float4(v4, v5, v6, v7);
    }
    __syncthreads();

    // gemm2: lane g computes output cols 4g..4g+3 of its node
    float o0 = 0.f, o1 = 0.f, o2 = 0.f, o3 = 0.f;
#pragma unroll 4
    for (int k = 0; k < 128; k++) {
        float hv = hs[nl * 128 + k];                       // broadcast
        uint2 pw = *(const uint2*)&W2s[k * 32 + (g << 1)]; // conflict-free
        o0 += hv * bflo(pw.x); o1 += hv * bfhi(pw.x);
        o2 += hv * bflo(pw.y); o3 += hv * bfhi(pw.y);
    }
    if (active)
        ((uint2*)xb2)[d * 16 + g] = make_uint2(pack2bf(o0, o1), pack2bf(o2, o3));
}

// ---- gather2 (+dinv, bias, PReLU) fused with half-sum readout -------------
// 8 node-pairs (j, j+half)/block, 16 lanes/node, 4 ch/lane. Skip etype==0.
__global__ __launch_bounds__(256) void k_g2h(const unsigned* __restrict__ lensw,
                                             const int2* __restrict__ ell,
                                             const unsigned* __restrict__ xb2,
                                             const float* __restrict__ dinv2,
                                             const float* __restrict__ b,
                                             const float* __restrict__ alpha,
                                             float* __restrict__ out, int half, int n) {
    __shared__ float fs[8 * 64];         // 2 KB
    int t = threadIdx.x;
    int slot = t >> 4;                   // 0..15
    int g = t & 15;
    int base = blockIdx.x * 8;
    int j = base + ((slot < 8) ? slot : (slot - 8));
    int d = (slot < 8) ? j : (j + half);
    bool active = j < half;
    unsigned lw = active ? lensw[d] : 0u;
    const uint2* x2 = (const uint2*)xb2;

    float a0 = 0.f, a1 = 0.f, a2 = 0.f, a3 = 0.f;
    for (int seg = 0; seg < SEG; seg++) {
        int len = (lw >> (seg * 8)) & 0xFF;
        const int2* rowp = ell + ((size_t)seg * n + d) * CAP;
        for (int k0 = 0; k0 < len; k0 += 16) {
            int kk = k0 + g;
            int2 ent = make_int2(0, 0);
            float cf = 0.f;
            if (kk < len) {
                ent = rowp[kk];
                int tt = ((unsigned)ent.x) >> 24;
                if (tt) cf = (float)tt * dinv2[ent.x & 0xFFFFFF];   // et*dinv2[src]
            }
            int m = min(16, len - k0);
            for (int jj = 0; jj < m; jj++) {
                int pej = __shfl(ent.x, jj, 16);
                float cj = __shfl(cf, jj, 16);
                if (cj != 0.f) {
                    int s = pej & 0xFFFFFF;
                    uint2 q = x2[(size_t)s * 16 + g];
                    a0 += bflo(q.x) * cj; a1 += bfhi(q.x) * cj;
                    a2 += bflo(q.y) * cj; a3 += bfhi(q.y) * cj;
                }
            }
        }
    }

    float f0 = 0.f, f1 = 0.f, f2 = 0.f, f3 = 0.f;
    if (active) {
        float di = dinv2[d];
        uint2 sq = x2[(size_t)d * 16 + g];
        int c4 = g << 2;
        float4 bv = *(const float4*)&b[c4];
        float4 av = *(const float4*)&alpha[c4];
        f0 = di * (a0 + bflo(sq.x) * di) + bv.x; f0 = f0 >= 0.f ? f0 : av.x * f0;
        f1 = di * (a1 + bfhi(sq.x) * di) + bv.y; f1 = f1 >= 0.f ? f1 : av.y * f1;
        f2 = di * (a2 + bflo(sq.y) * di) + bv.z; f2 = f2 >= 0.f ? f2 : av.z * f2;
        f3 = di * (a3 + bfhi(sq.y) * di) + bv.w; f3 = f3 >= 0.f ? f3 : av.w * f3;
    }
    if (slot >= 8)
        *(float4*)&fs[(slot - 8) * 64 + (g << 2)] = make_float4(f0, f1, f2, f3);
    __syncthreads();
    if (slot < 8 && active) {
        float4 p = *(const float4*)&fs[slot * 64 + (g << 2)];
        ((float4*)out)[j * 16 + g] = make_float4(0.5f * (f0 + p.x), 0.5f * (f1 + p.y),
                                                 0.5f * (f2 + p.z), 0.5f * (f3 + p.w));
    }
}

extern "C" void kernel_launch(void* const* d_in, const int* in_sizes, int n_in,
                              void* d_out, int out_size, void* d_ws, size_t ws_size,
                              hipStream_t stream) {
    const float* x  = (const float*)d_in[0];
    const int*   ei = (const int*)d_in[1];
    const float* ew = (const float*)d_in[2];
    const int*   et = (const int*)d_in[3];
    const float* W1 = (const float*)d_in[4];
    const float* b1 = (const float*)d_in[5];
    const float* a1 = (const float*)d_in[6];
    const float* W2 = (const float*)d_in[7];
    const float* b2 = (const float*)d_in[8];
    const float* a2 = (const float*)d_in[9];

    const int N = in_sizes[0] / 128;   // 100000
    const int E = in_sizes[1] / 2;     // 1600000
    const int* src = ei;
    const int* dst = ei + E;

    // Workspace (4-byte words), ~131 MB:
    //   dinv1 N | dinv2 N | lensw N | xb1 64N | xb2 32N | cnt 4N | ell 224N
    float*    ws    = (float*)d_ws;
    float*    dinv1 = ws;
    float*    dinv2 = dinv1 + N;
    unsigned* lensw = (unsigned*)(dinv2 + N);
    unsigned* xb1   = lensw + N;
    unsigned* xb2   = xb1 + (size_t)N * 64;
    int*      cnt   = (int*)(xb2 + (size_t)N * 32);
    int2*     ell   = (int2*)(cnt + (size_t)SEG * N);

    hipMemsetAsync(cnt, 0, (size_t)SEG * N * sizeof(int), stream);

    k_gemm1<<<(N + 31) / 32, 256, 0, stream>>>(x, W1, xb1, N);

    k_ell<<<(E + 255) / 256, 256, 0, stream>>>(src, dst, et, ew, cnt, ell, E, N);

    k_dinv<<<(N + 15) / 16, 256, 0, stream>>>(cnt, ell, dinv1, dinv2, lensw, N);

    k_g1g2<<<(N + 15) / 16, 256, 0, stream>>>(lensw, ell, xb1, dinv1, b1, a1,
                                              W2, xb2, N);

    k_g2h<<<(N / 2 + 7) / 8, 256, 0, stream>>>(lensw, ell, xb2, dinv2, b2, a2,
                                               (float*)d_out, N / 2, N);
}